// Round 3
// baseline (170.166 us; speedup 1.0000x reference)
//
#include <hip/hip_runtime.h>
#include <math.h>

// ---------------------------------------------------------------------------
// QConv2dMedium: quantum conv = per-pixel 16-ch map
//   out[k] = clip(8 * |U[k,0:9] . p|^2 / max(||p||,1e-12)^2, 0, 1)
// U = (CNOT perms L1)(Layer1)(CNOT perms L0)(Layer0), 16x16 complex.
//
// R1: 4 px/thread + packed U in LDS (ds_read_b128): -9us.
// R2: nt stores + launch_bounds(256,4): neutral (write-allocate theory
//     bounded at <=1:1 evictions; qconv is ~30us vs 22.6us write roofline).
// R3: fuse build_unitary into qconv (each block rebuilds U: 256 threads =
//     16x16 (r,c) grid; CNOT perms folded into matmul indices so only
//     L0/L1 live in LDS). Removes a serialized 1-block graph node + the
//     u round-trip (~5-8us of latency). Row staging issues before trig.
// ---------------------------------------------------------------------------

#define WIRES 4
#define DIM 16

typedef float f32x4 __attribute__((ext_vector_type(4)));

// Rot(phi, theta, omega) entry [rb][cb] of wire i's 2x2, as complex (er, ei)
__device__ inline void rot_entry(float phi, float th, float om, int rb, int cb,
                                 float& er, float& ei) {
    float a = 0.5f * (phi + om);
    float b = 0.5f * (phi - om);
    float cc = cosf(0.5f * th), ss = sinf(0.5f * th);
    if (rb == 0 && cb == 0) { er = cc * cosf(a); ei = -cc * sinf(a); }
    else if (rb == 0 && cb == 1) { er = -ss * cosf(b); ei = -ss * sinf(b); }
    else if (rb == 1 && cb == 0) { er = ss * cosf(b); ei = -ss * sinf(b); }
    else { er = cc * cosf(a); ei = cc * sinf(a); }
}

// layer element L[r][c] = prod_i R_i[bit_i(r)][bit_i(c)], bit_i = bit (3-i)
__device__ inline void layer_elem(const float* __restrict__ w, int l, int r,
                                  int c, float& pr, float& pi) {
    pr = 1.f; pi = 0.f;
    #pragma unroll
    for (int i = 0; i < WIRES; ++i) {
        const float* wi = w + (l * WIRES + i) * 3;
        float er, ei;
        int rb = (r >> (3 - i)) & 1, cb = (c >> (3 - i)) & 1;
        rot_entry(wi[0], wi[1], wi[2], rb, cb, er, ei);
        float nr = pr * er - pi * ei;
        float ni = pr * ei + pi * er;
        pr = nr; pi = ni;
    }
}

// source row after applying the layer-l CNOT chain (dest row r reads src row)
__device__ inline int cnot_src(int r, int range) {
    int src = r;
    // U_final[j] = U[p0(p1(p2(p3(j))))] -> apply p3 first
    #pragma unroll
    for (int i = WIRES - 1; i >= 0; --i) {
        int control = i, target = (i + range) & 3;
        int cbit = 1 << (3 - control), tbit = 1 << (3 - target);
        if (src & cbit) src ^= tbit;
    }
    return src;
}

#define H 256
#define W 256
#define NB 32
#define OUTC 16
#define RPB 4   // output rows per block; thread t: row t>>6, cols 4*(t&63)..+3

__global__ __launch_bounds__(256, 4) void qconv_kernel(
        const float* __restrict__ x, const float* __restrict__ w,
        float* __restrict__ out) {
    __shared__ float L0r[DIM][DIM], L0i[DIM][DIM];   // layer-0 factor
    __shared__ float L1r[DIM][DIM], L1i[DIM][DIM];   // layer-1 factor
    __shared__ float sU[OUTC][20];           // interleaved re,im; 18 used/row
    __shared__ float rows[RPB + 2][W + 8];   // rows[wr][j+1] = x[i0-1+wr][j]

    int t = threadIdx.x;
    int blk = blockIdx.x;            // 0 .. NB*H/RPB - 1
    int b = blk >> 6;                // 64 row-groups per image
    int i0 = (blk & 63) << 2;

    // ---- stage 6 input rows first (global loads issue before the trig) ----
    const float* xb = x + (size_t)b * (H * W);
    #pragma unroll
    for (int wr = 0; wr < RPB + 2; ++wr) {
        int row = i0 + wr - 1;
        bool rok = (unsigned)row < (unsigned)H;
        for (int cpos = t; cpos < W + 2; cpos += 256) {
            int j = cpos - 1;
            float v = 0.01f;
            if (rok && (unsigned)j < (unsigned)W) v = xb[row * W + j];
            rows[wr][cpos] = v;
        }
    }

    // ---- build U in-block: thread t = element (r,c) of the 16x16 ----
    int ur = t >> 4, uc = t & 15;
    {
        float lr, li;
        layer_elem(w, 0, ur, uc, lr, li);
        L0r[ur][uc] = lr; L0i[ur][uc] = li;
        layer_elem(w, 1, ur, uc, lr, li);
        L1r[ur][uc] = lr; L1i[ur][uc] = li;
    }
    __syncthreads();
    // U[r][c] = sum_m L1[s1(r)][m] * L0[p0(m)][c]   (CNOT perms folded in)
    if (uc < 9) {
        int s1 = cnot_src(ur, 2);    // layer-1 chain, range = 1%3+1 = 2
        float ar = 0.f, ai = 0.f;
        #pragma unroll
        for (int m = 0; m < DIM; ++m) {
            int p0 = cnot_src(m, 1); // layer-0 chain, range = 0%3+1 = 1 (const)
            float xr = L1r[s1][m], xi = L1i[s1][m];
            float yr = L0r[p0][uc], yi = L0i[p0][uc];
            ar += xr * yr - xi * yi;
            ai += xr * yi + xi * yr;
        }
        sU[ur][2 * uc]     = ar;
        sU[ur][2 * uc + 1] = ai;
    }
    __syncthreads();

    int rl = t >> 6;                 // local output row 0..3
    int c  = (t & 63) << 2;          // column base 0..252 (16B-aligned)
    int i  = i0 + rl;

    // ---- sliding window: 3 input rows x 6 cols (cols c-1 .. c+4 of x) ----
    float win[3][6];
    #pragma unroll
    for (int di = 0; di < 3; ++di) {
        float4 a = *(const float4*)&rows[rl + di][c];       // u=0..3
        float4 bq = *(const float4*)&rows[rl + di][c + 4];  // u=4..7 (6,7 unused)
        win[di][0] = a.x;  win[di][1] = a.y;  win[di][2] = a.z;
        win[di][3] = a.w;  win[di][4] = bq.x; win[di][5] = bq.y;
    }

    // ---- per-pixel norm factor ----
    float fac[4];
    #pragma unroll
    for (int px = 0; px < 4; ++px) {
        float n2 = 0.f;
        #pragma unroll
        for (int di = 0; di < 3; ++di)
            #pragma unroll
            for (int dj = 0; dj < 3; ++dj) {
                float pv = win[di][px + dj];
                n2 = fmaf(pv, pv, n2);
            }
        // (DIM*0.5)/max(||p||,1e-12)^2 ; max(n,e)^2 == max(n^2,e^2) for n>=0
        fac[px] = 8.0f / fmaxf(n2, 1e-24f);
    }

    // ---- 16 channels, 4 pixels each; nontemporal float4 coalesced stores ----
    float* ob = out + (size_t)b * OUTC * (H * W) + (size_t)i * W + c;
    #pragma unroll
    for (int k = 0; k < OUTC; ++k) {
        float4 q0 = *(const float4*)&sU[k][0];    // m0,m1 (re,im)
        float4 q1 = *(const float4*)&sU[k][4];    // m2,m3
        float4 q2 = *(const float4*)&sU[k][8];    // m4,m5
        float4 q3 = *(const float4*)&sU[k][12];   // m6,m7
        float2 q4 = *(const float2*)&sU[k][16];   // m8
        f32x4 res;
        #pragma unroll
        for (int px = 0; px < 4; ++px) {
            float sr, si;
            sr = q0.x * win[0][px];                                 // m0
            si = q0.y * win[0][px];
            sr = fmaf(q0.z, win[0][px + 1], sr);                    // m1
            si = fmaf(q0.w, win[0][px + 1], si);
            sr = fmaf(q1.x, win[0][px + 2], sr);                    // m2
            si = fmaf(q1.y, win[0][px + 2], si);
            sr = fmaf(q1.z, win[1][px], sr);                        // m3
            si = fmaf(q1.w, win[1][px], si);
            sr = fmaf(q2.x, win[1][px + 1], sr);                    // m4
            si = fmaf(q2.y, win[1][px + 1], si);
            sr = fmaf(q2.z, win[1][px + 2], sr);                    // m5
            si = fmaf(q2.w, win[1][px + 2], si);
            sr = fmaf(q3.x, win[2][px], sr);                        // m6
            si = fmaf(q3.y, win[2][px], si);
            sr = fmaf(q3.z, win[2][px + 1], sr);                    // m7
            si = fmaf(q3.w, win[2][px + 1], si);
            sr = fmaf(q4.x, win[2][px + 2], sr);                    // m8
            si = fmaf(q4.y, win[2][px + 2], si);
            float v = fac[px] * fmaf(sr, sr, si * si);
            res[px] = fminf(v, 1.0f);
        }
        __builtin_nontemporal_store(res, (f32x4*)&ob[(size_t)k * (H * W)]);
    }
}

extern "C" void kernel_launch(void* const* d_in, const int* in_sizes, int n_in,
                              void* d_out, int out_size, void* d_ws, size_t ws_size,
                              hipStream_t stream) {
    const float* x = (const float*)d_in[0];        // (32,1,256,256) fp32
    const float* w = (const float*)d_in[1];        // (2,4,3) fp32
    float* out = (float*)d_out;                    // (32,16,256,256) fp32

    qconv_kernel<<<NB * H / RPB, 256, 0, stream>>>(x, w, out);
}

// Round 4
// 145.940 us; speedup vs baseline: 1.1660x; 1.1660x over previous
//
#include <hip/hip_runtime.h>
#include <math.h>

// ---------------------------------------------------------------------------
// QConv2dMedium: quantum conv = per-pixel 16-ch map
//   out[k] = clip(8 * |U[k,0:9] . p|^2 / max(||p||,1e-12)^2, 0, 1)
// U = (CNOT perms L1)(Layer1)(CNOT perms L0)(Layer0), 16x16 complex.
//
// R1: 4 px/thread + packed U in LDS (ds_read_b128): -9us.
// R2: nt stores + launch_bounds(256,4) bundled: +3.6us fill-normalized.
// R3: fused U-build into qconv: neutral (launch saved == redundant U cost).
// R4: REVERT the R2 bundle (plain float4 stores -- the poison fill proves
//     the normal store path does 6.4 TB/s; unclamp VGPR) + sincosf to halve
//     trig range-reductions in the U-build phase. Single-mechanism test:
//     if fill-normalized time recovers ~3-4us, R2's bundle was the regression.
// ---------------------------------------------------------------------------

#define WIRES 4
#define DIM 16

// Rot(phi, theta, omega) entry [rb][cb] of wire i's 2x2, as complex (er, ei)
//   (0,0): ( cc*cos a, -cc*sin a)   (0,1): (-ss*cos b, -ss*sin b)
//   (1,0): ( ss*cos b, -ss*sin b)   (1,1): ( cc*cos a,  cc*sin a)
// a = (phi+om)/2, b = (phi-om)/2, cc = cos(th/2), ss = sin(th/2)
__device__ inline void rot_entry(float phi, float th, float om, int rb, int cb,
                                 float& er, float& ei) {
    float a = 0.5f * (phi + om);
    float b = 0.5f * (phi - om);
    float ss, cc;
    sincosf(0.5f * th, &ss, &cc);
    float ang = (rb ^ cb) ? b : a;
    float sa, ca;
    sincosf(ang, &sa, &ca);
    float mag = (rb ^ cb) ? ss : cc;
    er = ((rb == 0) && (cb == 1)) ? (-mag * ca) : (mag * ca);
    ei = ((rb & cb) ? mag : -mag) * sa;
}

// layer element L[r][c] = prod_i R_i[bit_i(r)][bit_i(c)], bit_i = bit (3-i)
__device__ inline void layer_elem(const float* __restrict__ w, int l, int r,
                                  int c, float& pr, float& pi) {
    pr = 1.f; pi = 0.f;
    #pragma unroll
    for (int i = 0; i < WIRES; ++i) {
        const float* wi = w + (l * WIRES + i) * 3;
        float er, ei;
        int rb = (r >> (3 - i)) & 1, cb = (c >> (3 - i)) & 1;
        rot_entry(wi[0], wi[1], wi[2], rb, cb, er, ei);
        float nr = pr * er - pi * ei;
        float ni = pr * ei + pi * er;
        pr = nr; pi = ni;
    }
}

// source row after applying the layer-l CNOT chain (dest row r reads src row)
__device__ inline int cnot_src(int r, int range) {
    int src = r;
    // U_final[j] = U[p0(p1(p2(p3(j))))] -> apply p3 first
    #pragma unroll
    for (int i = WIRES - 1; i >= 0; --i) {
        int control = i, target = (i + range) & 3;
        int cbit = 1 << (3 - control), tbit = 1 << (3 - target);
        if (src & cbit) src ^= tbit;
    }
    return src;
}

#define H 256
#define W 256
#define NB 32
#define OUTC 16
#define RPB 4   // output rows per block; thread t: row t>>6, cols 4*(t&63)..+3

__global__ __launch_bounds__(256) void qconv_kernel(
        const float* __restrict__ x, const float* __restrict__ w,
        float* __restrict__ out) {
    __shared__ float L0r[DIM][DIM], L0i[DIM][DIM];   // layer-0 factor
    __shared__ float L1r[DIM][DIM], L1i[DIM][DIM];   // layer-1 factor
    __shared__ float sU[OUTC][20];           // interleaved re,im; 18 used/row
    __shared__ float rows[RPB + 2][W + 8];   // rows[wr][j+1] = x[i0-1+wr][j]

    int t = threadIdx.x;
    int blk = blockIdx.x;            // 0 .. NB*H/RPB - 1
    int b = blk >> 6;                // 64 row-groups per image
    int i0 = (blk & 63) << 2;

    // ---- stage 6 input rows first (global loads issue before the trig) ----
    const float* xb = x + (size_t)b * (H * W);
    #pragma unroll
    for (int wr = 0; wr < RPB + 2; ++wr) {
        int row = i0 + wr - 1;
        bool rok = (unsigned)row < (unsigned)H;
        for (int cpos = t; cpos < W + 2; cpos += 256) {
            int j = cpos - 1;
            float v = 0.01f;
            if (rok && (unsigned)j < (unsigned)W) v = xb[row * W + j];
            rows[wr][cpos] = v;
        }
    }

    // ---- build U in-block: thread t = element (r,c) of the 16x16 ----
    int ur = t >> 4, uc = t & 15;
    {
        float lr, li;
        layer_elem(w, 0, ur, uc, lr, li);
        L0r[ur][uc] = lr; L0i[ur][uc] = li;
        layer_elem(w, 1, ur, uc, lr, li);
        L1r[ur][uc] = lr; L1i[ur][uc] = li;
    }
    __syncthreads();
    // U[r][c] = sum_m L1[s1(r)][m] * L0[p0(m)][c]   (CNOT perms folded in)
    if (uc < 9) {
        int s1 = cnot_src(ur, 2);    // layer-1 chain, range = 1%3+1 = 2
        float ar = 0.f, ai = 0.f;
        #pragma unroll
        for (int m = 0; m < DIM; ++m) {
            int p0 = cnot_src(m, 1); // layer-0 chain, range = 0%3+1 = 1 (const)
            float xr = L1r[s1][m], xi = L1i[s1][m];
            float yr = L0r[p0][uc], yi = L0i[p0][uc];
            ar += xr * yr - xi * yi;
            ai += xr * yi + xi * yr;
        }
        sU[ur][2 * uc]     = ar;
        sU[ur][2 * uc + 1] = ai;
    }
    __syncthreads();

    int rl = t >> 6;                 // local output row 0..3
    int c  = (t & 63) << 2;          // column base 0..252 (16B-aligned)
    int i  = i0 + rl;

    // ---- sliding window: 3 input rows x 6 cols (cols c-1 .. c+4 of x) ----
    float win[3][6];
    #pragma unroll
    for (int di = 0; di < 3; ++di) {
        float4 a = *(const float4*)&rows[rl + di][c];       // u=0..3
        float4 bq = *(const float4*)&rows[rl + di][c + 4];  // u=4..7 (6,7 unused)
        win[di][0] = a.x;  win[di][1] = a.y;  win[di][2] = a.z;
        win[di][3] = a.w;  win[di][4] = bq.x; win[di][5] = bq.y;
    }

    // ---- per-pixel norm factor ----
    float fac[4];
    #pragma unroll
    for (int px = 0; px < 4; ++px) {
        float n2 = 0.f;
        #pragma unroll
        for (int di = 0; di < 3; ++di)
            #pragma unroll
            for (int dj = 0; dj < 3; ++dj) {
                float pv = win[di][px + dj];
                n2 = fmaf(pv, pv, n2);
            }
        // (DIM*0.5)/max(||p||,1e-12)^2 ; max(n,e)^2 == max(n^2,e^2) for n>=0
        fac[px] = 8.0f / fmaxf(n2, 1e-24f);
    }

    // ---- 16 channels, 4 pixels each; plain float4 coalesced stores ----
    float* ob = out + (size_t)b * OUTC * (H * W) + (size_t)i * W + c;
    #pragma unroll
    for (int k = 0; k < OUTC; ++k) {
        float4 q0 = *(const float4*)&sU[k][0];    // m0,m1 (re,im)
        float4 q1 = *(const float4*)&sU[k][4];    // m2,m3
        float4 q2 = *(const float4*)&sU[k][8];    // m4,m5
        float4 q3 = *(const float4*)&sU[k][12];   // m6,m7
        float2 q4 = *(const float2*)&sU[k][16];   // m8
        float4 res;
        #pragma unroll
        for (int px = 0; px < 4; ++px) {
            float sr, si;
            sr = q0.x * win[0][px];                                 // m0
            si = q0.y * win[0][px];
            sr = fmaf(q0.z, win[0][px + 1], sr);                    // m1
            si = fmaf(q0.w, win[0][px + 1], si);
            sr = fmaf(q1.x, win[0][px + 2], sr);                    // m2
            si = fmaf(q1.y, win[0][px + 2], si);
            sr = fmaf(q1.z, win[1][px], sr);                        // m3
            si = fmaf(q1.w, win[1][px], si);
            sr = fmaf(q2.x, win[1][px + 1], sr);                    // m4
            si = fmaf(q2.y, win[1][px + 1], si);
            sr = fmaf(q2.z, win[1][px + 2], sr);                    // m5
            si = fmaf(q2.w, win[1][px + 2], si);
            sr = fmaf(q3.x, win[2][px], sr);                        // m6
            si = fmaf(q3.y, win[2][px], si);
            sr = fmaf(q3.z, win[2][px + 1], sr);                    // m7
            si = fmaf(q3.w, win[2][px + 1], si);
            sr = fmaf(q4.x, win[2][px + 2], sr);                    // m8
            si = fmaf(q4.y, win[2][px + 2], si);
            float v = fac[px] * fmaf(sr, sr, si * si);
            ((float*)&res)[px] = fminf(v, 1.0f);
        }
        *(float4*)&ob[(size_t)k * (H * W)] = res;
    }
}

extern "C" void kernel_launch(void* const* d_in, const int* in_sizes, int n_in,
                              void* d_out, int out_size, void* d_ws, size_t ws_size,
                              hipStream_t stream) {
    const float* x = (const float*)d_in[0];        // (32,1,256,256) fp32
    const float* w = (const float*)d_in[1];        // (2,4,3) fp32
    float* out = (float*)d_out;                    // (32,16,256,256) fp32

    qconv_kernel<<<NB * H / RPB, 256, 0, stream>>>(x, w, out);
}

// Round 5
// 144.859 us; speedup vs baseline: 1.1747x; 1.0075x over previous
//
#include <hip/hip_runtime.h>
#include <math.h>

// ---------------------------------------------------------------------------
// QConv2dMedium: quantum conv = per-pixel 16-ch map
//   out[k] = clip(8 * |U[k,0:9] . p|^2 / max(||p||,1e-12)^2, 0, 1)
// U = (CNOT perms L1)(Layer1)(CNOT perms L0)(Layer0), 16x16 complex.
//
// R1: 4 px/thread + packed U in LDS (ds_read_b128): -9us.
// R2: nt stores + launch_bounds(256,4) bundled: +3.6us (reverted R4).
// R3: fused U-build into qconv: neutral.
// R4: revert R2 bundle + sincosf (halved trig): -24us -> trig is first-order.
// R5: (a) rot-entry LDS table: threads t<32 do the only 2 sincosf each;
//     layer_elem becomes LDS float2 reads + complex muls (bitwise-identical
//     order -> same absmax). (b) RPB 4->8 with 512-thread blocks: halves
//     block count -> halves U-build repetitions + halo loads.
// ---------------------------------------------------------------------------

#define WIRES 4
#define DIM 16

// source row after applying the layer-l CNOT chain (dest row r reads src row)
__device__ inline int cnot_src(int r, int range) {
    int src = r;
    // U_final[j] = U[p0(p1(p2(p3(j))))] -> apply p3 first
    #pragma unroll
    for (int i = WIRES - 1; i >= 0; --i) {
        int control = i, target = (i + range) & 3;
        int cbit = 1 << (3 - control), tbit = 1 << (3 - target);
        if (src & cbit) src ^= tbit;
    }
    return src;
}

#define H 256
#define W 256
#define NB 32
#define OUTC 16
#define RPB 8     // output rows per block (512 threads, 4 px each)
#define TPB 512

__global__ __launch_bounds__(TPB) void qconv_kernel(
        const float* __restrict__ x, const float* __restrict__ w,
        float* __restrict__ out) {
    // sRot[l][i][rb][cb] = (re,im) of wire-i Rot entry [rb][cb] in layer l
    __shared__ float2 sRot[2][WIRES][2][2];
    __shared__ float L0r[DIM][DIM], L0i[DIM][DIM];   // layer-0 factor
    __shared__ float L1r[DIM][DIM], L1i[DIM][DIM];   // layer-1 factor
    __shared__ float sU[OUTC][20];           // interleaved re,im; 18 used/row
    __shared__ float rows[RPB + 2][W + 8];   // rows[wr][j+1] = x[i0-1+wr][j]

    int t = threadIdx.x;
    int blk = blockIdx.x;            // 0 .. NB*H/RPB - 1
    int b = blk >> 5;                // 32 row-groups per image
    int i0 = (blk & 31) << 3;

    // ---- stage 10 input rows first (global loads issue before the trig) ----
    const float* xb = x + (size_t)b * (H * W);
    #pragma unroll
    for (int wr = 0; wr < RPB + 2; ++wr) {
        int row = i0 + wr - 1;
        bool rok = (unsigned)row < (unsigned)H;
        for (int cpos = t; cpos < W + 2; cpos += TPB) {
            int j = cpos - 1;
            float v = 0.01f;
            if (rok && (unsigned)j < (unsigned)W) v = xb[row * W + j];
            rows[wr][cpos] = v;
        }
    }

    // ---- rot-entry table: 32 threads, 2 sincosf each ----
    // Rot(phi,th,om) entries: a=(phi+om)/2, b=(phi-om)/2, cc=cos(th/2), ss=sin
    //   (0,0): ( cc*cos a, -cc*sin a)   (0,1): (-ss*cos b, -ss*sin b)
    //   (1,0): ( ss*cos b, -ss*sin b)   (1,1): ( cc*cos a,  cc*sin a)
    if (t < 32) {
        int l = t >> 4, i = (t >> 2) & 3, rb = (t >> 1) & 1, cb = t & 1;
        const float* wi = w + (l * WIRES + i) * 3;
        float phi = wi[0], th = wi[1], om = wi[2];
        float a = 0.5f * (phi + om);
        float bb = 0.5f * (phi - om);
        float ss, cc;
        sincosf(0.5f * th, &ss, &cc);
        float ang = (rb ^ cb) ? bb : a;
        float sa, ca;
        sincosf(ang, &sa, &ca);
        float mag = (rb ^ cb) ? ss : cc;
        float er = ((rb == 0) && (cb == 1)) ? (-mag * ca) : (mag * ca);
        float ei = ((rb & cb) ? mag : -mag) * sa;
        sRot[l][i][rb][cb] = make_float2(er, ei);
    }
    __syncthreads();

    // ---- L elements from the table: thread t<256 = (r,c) of the 16x16 ----
    int ur = t >> 4, uc = t & 15;
    if (t < 256) {
        #pragma unroll
        for (int l = 0; l < 2; ++l) {
            float pr = 1.f, pi = 0.f;
            #pragma unroll
            for (int i = 0; i < WIRES; ++i) {
                int rb = (ur >> (3 - i)) & 1, cb = (uc >> (3 - i)) & 1;
                float2 e = sRot[l][i][rb][cb];
                float nr = pr * e.x - pi * e.y;
                float ni = pr * e.y + pi * e.x;
                pr = nr; pi = ni;
            }
            if (l == 0) { L0r[ur][uc] = pr; L0i[ur][uc] = pi; }
            else        { L1r[ur][uc] = pr; L1i[ur][uc] = pi; }
        }
    }
    __syncthreads();
    // U[r][c] = sum_m L1[s1(r)][m] * L0[p0(m)][c]   (CNOT perms folded in)
    if (t < 256 && uc < 9) {
        int s1 = cnot_src(ur, 2);    // layer-1 chain, range = 1%3+1 = 2
        float ar = 0.f, ai = 0.f;
        #pragma unroll
        for (int m = 0; m < DIM; ++m) {
            int p0 = cnot_src(m, 1); // layer-0 chain, range = 0%3+1 = 1 (const)
            float xr = L1r[s1][m], xi = L1i[s1][m];
            float yr = L0r[p0][uc], yi = L0i[p0][uc];
            ar += xr * yr - xi * yi;
            ai += xr * yi + xi * yr;
        }
        sU[ur][2 * uc]     = ar;
        sU[ur][2 * uc + 1] = ai;
    }
    __syncthreads();

    int rl = t >> 6;                 // local output row 0..7
    int c  = (t & 63) << 2;          // column base 0..252 (16B-aligned)
    int i  = i0 + rl;

    // ---- sliding window: 3 input rows x 6 cols (cols c-1 .. c+4 of x) ----
    float win[3][6];
    #pragma unroll
    for (int di = 0; di < 3; ++di) {
        float4 a = *(const float4*)&rows[rl + di][c];       // u=0..3
        float4 bq = *(const float4*)&rows[rl + di][c + 4];  // u=4..7 (6,7 unused)
        win[di][0] = a.x;  win[di][1] = a.y;  win[di][2] = a.z;
        win[di][3] = a.w;  win[di][4] = bq.x; win[di][5] = bq.y;
    }

    // ---- per-pixel norm factor ----
    float fac[4];
    #pragma unroll
    for (int px = 0; px < 4; ++px) {
        float n2 = 0.f;
        #pragma unroll
        for (int di = 0; di < 3; ++di)
            #pragma unroll
            for (int dj = 0; dj < 3; ++dj) {
                float pv = win[di][px + dj];
                n2 = fmaf(pv, pv, n2);
            }
        // (DIM*0.5)/max(||p||,1e-12)^2 ; max(n,e)^2 == max(n^2,e^2) for n>=0
        fac[px] = 8.0f / fmaxf(n2, 1e-24f);
    }

    // ---- 16 channels, 4 pixels each; plain float4 coalesced stores ----
    float* ob = out + (size_t)b * OUTC * (H * W) + (size_t)i * W + c;
    #pragma unroll
    for (int k = 0; k < OUTC; ++k) {
        float4 q0 = *(const float4*)&sU[k][0];    // m0,m1 (re,im)
        float4 q1 = *(const float4*)&sU[k][4];    // m2,m3
        float4 q2 = *(const float4*)&sU[k][8];    // m4,m5
        float4 q3 = *(const float4*)&sU[k][12];   // m6,m7
        float2 q4 = *(const float2*)&sU[k][16];   // m8
        float4 res;
        #pragma unroll
        for (int px = 0; px < 4; ++px) {
            float sr, si;
            sr = q0.x * win[0][px];                                 // m0
            si = q0.y * win[0][px];
            sr = fmaf(q0.z, win[0][px + 1], sr);                    // m1
            si = fmaf(q0.w, win[0][px + 1], si);
            sr = fmaf(q1.x, win[0][px + 2], sr);                    // m2
            si = fmaf(q1.y, win[0][px + 2], si);
            sr = fmaf(q1.z, win[1][px], sr);                        // m3
            si = fmaf(q1.w, win[1][px], si);
            sr = fmaf(q2.x, win[1][px + 1], sr);                    // m4
            si = fmaf(q2.y, win[1][px + 1], si);
            sr = fmaf(q2.z, win[1][px + 2], sr);                    // m5
            si = fmaf(q2.w, win[1][px + 2], si);
            sr = fmaf(q3.x, win[2][px], sr);                        // m6
            si = fmaf(q3.y, win[2][px], si);
            sr = fmaf(q3.z, win[2][px + 1], sr);                    // m7
            si = fmaf(q3.w, win[2][px + 1], si);
            sr = fmaf(q4.x, win[2][px + 2], sr);                    // m8
            si = fmaf(q4.y, win[2][px + 2], si);
            float v = fac[px] * fmaf(sr, sr, si * si);
            ((float*)&res)[px] = fminf(v, 1.0f);
        }
        *(float4*)&ob[(size_t)k * (H * W)] = res;
    }
}

extern "C" void kernel_launch(void* const* d_in, const int* in_sizes, int n_in,
                              void* d_out, int out_size, void* d_ws, size_t ws_size,
                              hipStream_t stream) {
    const float* x = (const float*)d_in[0];        // (32,1,256,256) fp32
    const float* w = (const float*)d_in[1];        // (2,4,3) fp32
    float* out = (float*)d_out;                    // (32,16,256,256) fp32

    qconv_kernel<<<NB * H / RPB, TPB, 0, stream>>>(x, w, out);
}